// Round 2
// baseline (1177.479 us; speedup 1.0000x reference)
//
#include <hip/hip_runtime.h>
#include <stdint.h>

// GenerativeWorldModel: B=2048,T=50,N=23,F=4,H=64,FUT=10. All I/O fp32.
// 1 wave = 1 batch. 8 waves/block (512 thr), 256 blocks = 1/CU.
// GRU matmuls via mfma_f32_32x32x16_f16 (fp16 operands, fp32 accum);
// GCN folded to K=5 fp32 VALU form:
//   spatial = relu( (adj@x) @ Wg^T + rowsum(adj) * b_gcn )
// Gate math / h-state / decoder feedback kept in fp32.

typedef _Float16 f16;
typedef f16   f16x8  __attribute__((ext_vector_type(8)));
typedef float f32x16 __attribute__((ext_vector_type(16)));
typedef float f32x4n __attribute__((ext_vector_type(4)));

// LDS map (bytes):
//  [0,55296): 54 B-fragments (fp16), 1024B each (frag*1024 + lane*16):
//    W_ih frag=nt*4+kt (nt 0..5, kt 0..3); W_hh +24; W_d1 48+kt; W_d2 52+kt (zero-pad n>=4)
//  55296 + wave*12480:
//    spat f16[32][72] (0) | hbuf f16[32][72] (4608) | adj f32[529] (9216)
//    | x f32[92] (11344) | ax f32[23][8] (11712)
#define PW_STRIDE 12480
#define SMEM_BYTES (55296 + 8 * PW_STRIDE)

__global__ __launch_bounds__(512, 2) void gwm_kernel(
    const float* __restrict__ xseq, const float* __restrict__ adjseq,
    const float* __restrict__ Wg,  const float* __restrict__ bg,
    const float* __restrict__ Wih, const float* __restrict__ Whh,
    const float* __restrict__ bih, const float* __restrict__ bhh,
    const float* __restrict__ Wd1, const float* __restrict__ bd1,
    const float* __restrict__ Wd2, const float* __restrict__ bd2,
    float* __restrict__ out)
{
    extern __shared__ char smem[];
    const int tid  = threadIdx.x;
    const int lane = tid & 63;
    const int wv   = tid >> 6;
    const int l31  = lane & 31;
    const int hf   = lane >> 5;

    // ---- pack fp32 weights into fp16 MFMA B-fragment order (once) ----
    for (int idx = tid; idx < 54 * 64; idx += 512) {
        const int fi = idx >> 6;
        const int l  = idx & 63;
        const int ln = l & 31, lh = l >> 5;
        const float* src = nullptr;
        if (fi < 24) {                       // W_ih: B[k][n]
            const int nt = fi >> 2, kt = fi & 3;
            src = Wih + (nt * 32 + ln) * 64 + kt * 16 + lh * 8;
        } else if (fi < 48) {                // W_hh
            const int f2 = fi - 24, nt = f2 >> 2, kt = f2 & 3;
            src = Whh + (nt * 32 + ln) * 64 + kt * 16 + lh * 8;
        } else if (fi < 52) {                // W_d1 (32x64)
            const int kt = fi - 48;
            src = Wd1 + ln * 64 + kt * 16 + lh * 8;
        } else {                             // W_d2 (4x32), n>=4 zero-padded
            const int kt = fi - 52;
            if (ln < 4) src = Wd2 + ln * 32 + kt * 16 + lh * 8;
        }
        f16x8 h;
        if (src) {
            const f32x4n v0 = *(const f32x4n*)src;
            const f32x4n v1 = *(const f32x4n*)(src + 4);
            #pragma unroll
            for (int j = 0; j < 4; ++j) { h[j] = (f16)v0[j]; h[4 + j] = (f16)v1[j]; }
        } else {
            #pragma unroll
            for (int j = 0; j < 8; ++j) h[j] = (f16)0.f;
        }
        *(f16x8*)(smem + fi * 1024 + l * 16) = h;
    }

    char*  wbase = smem + 55296 + wv * PW_STRIDE;
    f16*   spat  = (f16*)(wbase);            // [32][72], row stride 144 B
    f16*   hbuf  = (f16*)(wbase + 4608);     // [32][72]
    float* adjL  = (float*)(wbase + 9216);   // [529]
    float* xL    = (float*)(wbase + 11344);  // [92]
    float* axL   = (float*)(wbase + 11712);  // [23][8] (ax[0..3], rowsum at +4)

    // zero h buffer (h0 = 0; fp16 zero bits == 0)
    for (int i = lane; i < 288; i += 64)
        *(uint4*)(wbase + 4608 + i * 16) = make_uint4(0u, 0u, 0u, 0u);

    __syncthreads();  // weight frags visible to all waves

    // ---- per-lane fp32 constants (held in VGPRs across all 60 steps) ----
    float wg0[4], wg1[4];
    #pragma unroll
    for (int f = 0; f < 4; ++f) {
        wg0[f] = Wg[(2 * l31) * 4 + f];
        wg1[f] = Wg[(2 * l31 + 1) * 4 + f];
    }
    const float bg0 = bg[2 * l31], bg1 = bg[2 * l31 + 1];
    float bIH[6], bHH[6];
    #pragma unroll
    for (int nt = 0; nt < 6; ++nt) {
        bIH[nt] = bih[nt * 32 + l31];
        bHH[nt] = bhh[nt * 32 + l31];
    }
    const float bD1 = bd1[l31];
    const float bD2 = (l31 < 4) ? bd2[l31] : 0.0f;

    const int b = blockIdx.x * 8 + wv;
    const float* xg = xseq   + (size_t)b * (50 * 92);
    const float* ag = adjseq + (size_t)b * (50 * 529);

    f32x16 hc0, hc1;   // h in fp32, C-layout (cols 0..31 / 32..63)
    #pragma unroll
    for (int i = 0; i < 16; ++i) { hc0[i] = 0.f; hc1[i] = 0.f; }

    for (int t = 0; t < 60; ++t) {
        // ---- stage x_t, adj_t (history only; future reuses adj[49], x = decoded) ----
        if (t < 50) {
            const float* asrc = ag + t * 529;
            for (int i = lane; i < 529; i += 64) adjL[i] = asrc[i];
            const float* xsrc = xg + t * 92;
            if (lane < 92 - 64) xL[lane + 64] = xsrc[lane + 64];
            if (lane < 64)      xL[lane]      = xsrc[lane];
        }

        // ---- ax = adj@x (23x4), rowsum(adj): lanes 0..22, fp32 ----
        if (lane < 23) {
            float a0 = 0.f, a1 = 0.f, a2 = 0.f, a3 = 0.f, a4 = 0.f;
            for (int m = 0; m < 23; ++m) {
                const float a = adjL[lane * 23 + m];
                const f32x4n xv = *(const f32x4n*)(xL + m * 4);  // broadcast
                a0 += a * xv[0]; a1 += a * xv[1];
                a2 += a * xv[2]; a3 += a * xv[3];
                a4 += a;
            }
            f32x4n r4; r4[0] = a0; r4[1] = a1; r4[2] = a2; r4[3] = a3;
            *(f32x4n*)(axL + lane * 8) = r4;
            axL[lane * 8 + 4] = a4;
        }

        // ---- spatial = relu(ax@Wg^T + rowsum*b_gcn) -> fp16 A-layout [m][k] ----
        #pragma unroll
        for (int it = 0; it < 12; ++it) {
            const int m = it * 2 + hf;
            if (m < 23) {
                const f32x4n axv = *(const f32x4n*)(axL + m * 8);
                const float  ar  = axL[m * 8 + 4];
                float s0 = ar * bg0, s1 = ar * bg1;
                #pragma unroll
                for (int f = 0; f < 4; ++f) { s0 += axv[f] * wg0[f]; s1 += axv[f] * wg1[f]; }
                s0 = fmaxf(s0, 0.f); s1 = fmaxf(s1, 0.f);
                union { f16 h[2]; unsigned int u; } pk;
                pk.h[0] = (f16)s0; pk.h[1] = (f16)s1;
                *(unsigned int*)((char*)spat + m * 144 + l31 * 4) = pk.u;
            }
        }

        // ---- A-fragments: spatial (this step), h (previous step) ----
        f16x8 aS[4], aH[4];
        #pragma unroll
        for (int kt = 0; kt < 4; ++kt) {
            aS[kt] = *(const f16x8*)((char*)spat + l31 * 144 + kt * 32 + hf * 16);
            aH[kt] = *(const f16x8*)((char*)hbuf + l31 * 144 + kt * 32 + hf * 16);
        }

        // ---- GRU: gi/gh via MFMA, gates elementwise in fp32 C-layout ----
        #pragma unroll
        for (int jt = 0; jt < 2; ++jt) {        // hidden cols [32*jt, 32*jt+32)
            f32x16 aIR, aIZ, aIN, aHR, aHZ, aHN;
            #pragma unroll
            for (int i = 0; i < 16; ++i) {
                aIR[i] = bIH[jt];  aIZ[i] = bIH[2 + jt];  aIN[i] = bIH[4 + jt];
                aHR[i] = bHH[jt];  aHZ[i] = bHH[2 + jt];  aHN[i] = bHH[4 + jt];
            }
            #pragma unroll
            for (int kt = 0; kt < 4; ++kt) {
                const f16x8 bIR = *(const f16x8*)(smem + ((jt) * 4 + kt) * 1024 + lane * 16);
                const f16x8 bIZ = *(const f16x8*)(smem + ((2 + jt) * 4 + kt) * 1024 + lane * 16);
                const f16x8 bIN = *(const f16x8*)(smem + ((4 + jt) * 4 + kt) * 1024 + lane * 16);
                const f16x8 bHR = *(const f16x8*)(smem + (24 + (jt) * 4 + kt) * 1024 + lane * 16);
                const f16x8 bHZ = *(const f16x8*)(smem + (24 + (2 + jt) * 4 + kt) * 1024 + lane * 16);
                const f16x8 bHN = *(const f16x8*)(smem + (24 + (4 + jt) * 4 + kt) * 1024 + lane * 16);
                aIR = __builtin_amdgcn_mfma_f32_32x32x16_f16(aS[kt], bIR, aIR, 0, 0, 0);
                aHR = __builtin_amdgcn_mfma_f32_32x32x16_f16(aH[kt], bHR, aHR, 0, 0, 0);
                aIZ = __builtin_amdgcn_mfma_f32_32x32x16_f16(aS[kt], bIZ, aIZ, 0, 0, 0);
                aHZ = __builtin_amdgcn_mfma_f32_32x32x16_f16(aH[kt], bHZ, aHZ, 0, 0, 0);
                aIN = __builtin_amdgcn_mfma_f32_32x32x16_f16(aS[kt], bIN, aIN, 0, 0, 0);
                aHN = __builtin_amdgcn_mfma_f32_32x32x16_f16(aH[kt], bHN, aHN, 0, 0, 0);
            }
            f32x16 hcv = (jt == 0) ? hc0 : hc1;
            #pragma unroll
            for (int i = 0; i < 16; ++i) {
                const float gr = aIR[i] + aHR[i];
                const float gz = aIZ[i] + aHZ[i];
                const float r  = __builtin_amdgcn_rcpf(1.f + __expf(-gr));
                const float z  = __builtin_amdgcn_rcpf(1.f + __expf(-gz));
                const float np = aIN[i] + r * aHN[i];
                const float th = 1.f - 2.f * __builtin_amdgcn_rcpf(1.f + __expf(2.f * np));
                const float hn = th + z * (hcv[i] - th);
                hcv[i] = hn;
                const int row = (i & 3) + 8 * (i >> 2) + 4 * hf;  // verified C/D row map
                hbuf[row * 72 + jt * 32 + l31] = (f16)hn;
            }
            if (jt == 0) hc0 = hcv; else hc1 = hcv;
        }

        // ---- future: decode h -> prediction and next x (fp32 feedback) ----
        if (t >= 50) {
            const int fs = t - 50;
            f32x16 d1a;
            #pragma unroll
            for (int i = 0; i < 16; ++i) d1a[i] = bD1;
            #pragma unroll
            for (int kt = 0; kt < 4; ++kt) {
                const f16x8 ah = *(const f16x8*)((char*)hbuf + l31 * 144 + kt * 32 + hf * 16);
                const f16x8 bw = *(const f16x8*)(smem + (48 + kt) * 1024 + lane * 16);
                d1a = __builtin_amdgcn_mfma_f32_32x32x16_f16(ah, bw, d1a, 0, 0, 0);
            }
            #pragma unroll
            for (int i = 0; i < 16; ++i) {     // relu(d1) -> A-layout (reuse spat)
                const int row = (i & 3) + 8 * (i >> 2) + 4 * hf;
                spat[row * 72 + l31] = (f16)fmaxf(d1a[i], 0.f);
            }
            f32x16 d2a;
            #pragma unroll
            for (int i = 0; i < 16; ++i) d2a[i] = bD2;
            #pragma unroll
            for (int kt = 0; kt < 2; ++kt) {
                const f16x8 ad = *(const f16x8*)((char*)spat + l31 * 144 + kt * 32 + hf * 16);
                const f16x8 bw = *(const f16x8*)(smem + (52 + kt) * 1024 + lane * 16);
                d2a = __builtin_amdgcn_mfma_f32_32x32x16_f16(ad, bw, d2a, 0, 0, 0);
            }
            if (l31 < 4) {
                #pragma unroll
                for (int i = 0; i < 16; ++i) {
                    const int row = (i & 3) + 8 * (i >> 2) + 4 * hf;
                    if (row < 23) {
                        const float v = d2a[i];
                        out[(size_t)b * 920 + fs * 92 + row * 4 + l31] = v;
                        xL[row * 4 + l31] = v;   // feeds next future step
                    }
                }
            }
        }
    }
}

extern "C" void kernel_launch(void* const* d_in, const int* in_sizes, int n_in,
                              void* d_out, int out_size, void* d_ws, size_t ws_size,
                              hipStream_t stream) {
    (void)in_sizes; (void)n_in; (void)d_ws; (void)ws_size; (void)out_size;
    hipFuncSetAttribute((const void*)gwm_kernel,
                        hipFuncAttributeMaxDynamicSharedMemorySize, SMEM_BYTES);
    gwm_kernel<<<dim3(256), dim3(512), SMEM_BYTES, stream>>>(
        (const float*)d_in[0], (const float*)d_in[1], (const float*)d_in[2],
        (const float*)d_in[3], (const float*)d_in[4], (const float*)d_in[5],
        (const float*)d_in[6], (const float*)d_in[7], (const float*)d_in[8],
        (const float*)d_in[9], (const float*)d_in[10], (const float*)d_in[11],
        (float*)d_out);
}